// Round 10
// baseline (153.656 us; speedup 1.0000x reference)
//
#include <hip/hip_runtime.h>

#define ALPHA 0.2f
#define NN 4096
#define IN_DIM 128
#define REPR 64
#define HEADS 8
#define NCOL 640   // 512 numerator + 8 denominator + 120 pad (never read)
#define KSPLIT 8
#define PLANE_ELEMS (NN * NCOL)

typedef _Float16 f16;
typedef _Float16 f16x2 __attribute__((ext_vector_type(2)));
typedef _Float16 f16x8 __attribute__((ext_vector_type(8)));
typedef float f32x4 __attribute__((ext_vector_type(4)));

union F16x8U { f16 e[8]; f16x8 v; };
union F16x8B { f16x2 h2[4]; f16x8 v; };

static __device__ __forceinline__ f16x2 cvt_pk(float x, float y) {
  return __builtin_bit_cast(f16x2, __builtin_amdgcn_cvt_pkrtz(x, y));
}

// ws layout (bytes) — ws_size = 256 MiB
#define WS_P   0u            // 8*4096*640*2 = 41943040
#define WS_HID 41943040u     // 8388608
#define WS_F2  50331648u     // 131072
#define WS_MX  50462720u     // 4096
#define WS_MT  50466816u     // 640*4096*2 = 5242880
#define WS_END 55709696u

// ---------- k1: hidden[i,j,l] = sum_k node[j,k]*W[i,k,l] (fp32) + fused f2 ----------
__global__ __launch_bounds__(256) void k_hidden(const float* __restrict__ node,
                                                const float* __restrict__ W,
                                                const float* __restrict__ sa,
                                                float* __restrict__ hidden,
                                                float* __restrict__ f2) {
  const int i = blockIdx.x;
  const int jb = blockIdx.y * 32;
  __shared__ float nl[32][137];
  __shared__ __align__(16) float wl[128][64];
  const int t = threadIdx.x;
  const float4* gn = (const float4*)(node + (size_t)jb * IN_DIM);
  #pragma unroll
  for (int q = 0; q < 4; ++q) {
    int i4 = q * 256 + t;
    int r = i4 >> 5, c4 = i4 & 31;
    float4 v = gn[i4];
    nl[r][c4*4+0] = v.x; nl[r][c4*4+1] = v.y; nl[r][c4*4+2] = v.z; nl[r][c4*4+3] = v.w;
  }
  const float4* gw = (const float4*)(W + (size_t)i * IN_DIM * REPR);
  #pragma unroll
  for (int q = 0; q < 8; ++q) {
    int i4 = q * 256 + t;
    int r = i4 >> 4, c4 = i4 & 15;
    *(float4*)&wl[r][c4*4] = gw[i4];
  }
  __syncthreads();
  const int tx = t & 15, ty = t >> 4;
  float acc0[4] = {0,0,0,0}, acc1[4] = {0,0,0,0};
  #pragma unroll 4
  for (int k = 0; k < 128; ++k) {
    float a0 = nl[2*ty][k], a1 = nl[2*ty+1][k];
    float4 b = *(const float4*)&wl[k][4*tx];
    acc0[0] += a0*b.x; acc0[1] += a0*b.y; acc0[2] += a0*b.z; acc0[3] += a0*b.w;
    acc1[0] += a1*b.x; acc1[1] += a1*b.y; acc1[2] += a1*b.z; acc1[3] += a1*b.w;
  }
  float* o0 = hidden + ((size_t)i*NN + jb + 2*ty) * REPR + 4*tx;
  *(float4*)o0 = make_float4(acc0[0],acc0[1],acc0[2],acc0[3]);
  *(float4*)(o0 + REPR) = make_float4(acc1[0],acc1[1],acc1[2],acc1[3]);

  float4 ad = *(const float4*)(sa + i * 2 * REPR + REPR + 4*tx);
  float s0 = 0.f, s1 = 0.f, x;
  x = acc0[0]; s0 += (x > 0.f ? x : ALPHA*x) * ad.x;
  x = acc0[1]; s0 += (x > 0.f ? x : ALPHA*x) * ad.y;
  x = acc0[2]; s0 += (x > 0.f ? x : ALPHA*x) * ad.z;
  x = acc0[3]; s0 += (x > 0.f ? x : ALPHA*x) * ad.w;
  x = acc1[0]; s1 += (x > 0.f ? x : ALPHA*x) * ad.x;
  x = acc1[1]; s1 += (x > 0.f ? x : ALPHA*x) * ad.y;
  x = acc1[2]; s1 += (x > 0.f ? x : ALPHA*x) * ad.z;
  x = acc1[3]; s1 += (x > 0.f ? x : ALPHA*x) * ad.w;
  #pragma unroll
  for (int d = 8; d > 0; d >>= 1) {
    s0 += __shfl_down(s0, d, 16);
    s1 += __shfl_down(s1, d, 16);
  }
  if (tx == 0) {
    f2[i*NN + jb + 2*ty]     = s0;
    f2[i*NN + jb + 2*ty + 1] = s1;
  }
}

// ---------- k3: per-head max of f2 ----------
__global__ __launch_bounds__(256) void k_max(const float* __restrict__ f2,
                                             float* __restrict__ mx) {
  const int i = blockIdx.x, t = threadIdx.x;
  __shared__ float red[256];
  float m = -1e30f;
  #pragma unroll
  for (int q = 0; q < 16; ++q) m = fmaxf(m, f2[i*NN + q*256 + t]);
  red[t] = m; __syncthreads();
  for (int s = 128; s > 0; s >>= 1) {
    if (t < s) red[t] = fmaxf(red[t], red[t + s]);
    __syncthreads();
  }
  if (t == 0) mx[i] = red[0];
}

// ---------- k4: M_T[i*64+l][k] = exp(f2[i,k]-mx[i]) * hidden[i,k,l]  (f16) ----------
__global__ __launch_bounds__(256) void k_mt_num(const float* __restrict__ hidden,
                                                const float* __restrict__ f2,
                                                const float* __restrict__ mx,
                                                f16* __restrict__ MT) {
  const int i = blockIdx.x;
  const int l = threadIdx.x & 63, q = threadIdx.x >> 6;
  const int k0 = blockIdx.y * 32 + q * 8;
  const float m = mx[i];
  float g[8];
  #pragma unroll
  for (int kk = 0; kk < 8; ++kk) g[kk] = __expf(f2[i*NN + k0 + kk] - m);
  F16x8U u;
  #pragma unroll
  for (int kk = 0; kk < 8; ++kk) {
    float h = hidden[((size_t)i*NN + k0 + kk) * REPR + l];
    u.e[kk] = (f16)(g[kk] * h);
  }
  *(f16x8*)&MT[(size_t)(i*REPR + l) * NN + k0] = u.v;
}

// ---------- k4b: M_T[512+i][k] = exp(f2[i,k]-mx[i]) ----------
__global__ __launch_bounds__(256) void k_mt_den(const float* __restrict__ f2,
                                               const float* __restrict__ mx,
                                               f16* __restrict__ MT) {
  const int gid = blockIdx.x * 256 + threadIdx.x;
  const int i = gid >> 9, kq = gid & 511, k0 = kq * 8;
  const float m = mx[i];
  F16x8U u;
  #pragma unroll
  for (int kk = 0; kk < 8; ++kk) u.e[kk] = (f16)__expf(f2[i*NN + k0 + kk] - m);
  *(f16x8*)&MT[(size_t)(512 + i) * NN + k0] = u.v;
}

// ---------- k6: NO-LDS direct-global MFMA GEMM ----------
// P[z][j][c] = sum_{k in split z} A[j,k] * MT[c,k]
// No LDS, no barriers: each wave owns a 64x128 output tile (mi=4, ni=8) and
// reads its MFMA fragments straight from global (L2-resident panels).
// A read fp32 (2x float4/frag) and converted in-reg via v_cvt_pkrtz (0/1
// exact). Per k-step (K=32): 8 A-loads + 8 B-loads + 16 cvt + 32 MFMA.
// Grid 640 = 16 jg x 5 ct x 8 zt; XCD-swizzled (640=8*80) so a jg's 5
// ct-blocks co-run on one XCD and share the A panel in L2.
__global__ __launch_bounds__(256) void k_gemm(const float* __restrict__ Af,
                                              const f16* __restrict__ MT,
                                              f16* __restrict__ P) {
  const int t = threadIdx.x;
  const int lane = t & 63, wid = t >> 6;

  const int lin = blockIdx.x;                // 0..639
  const int xcd = lin & 7, idx = lin >> 3;   // idx in [0,80)
  const int jg  = xcd + 8 * (idx / 40);      // 0..15
  const int r   = idx % 40;
  const int ct  = r % 5;                     // 0..4
  const int zt  = r / 5;                     // 0..7

  const int j0 = jg * 256 + wid * 64;        // wave's 64-row stripe
  const int c0 = ct * 128;
  const int kz = zt * 512;                   // 16 k-steps of 32
  const int frow = lane & 15, kg = lane >> 4;

  const float* pa[4];
  const f16*   pb[8];
  #pragma unroll
  for (int mi = 0; mi < 4; ++mi)
    pa[mi] = Af + (size_t)(j0 + mi*16 + frow) * NN + kz + kg*8;
  #pragma unroll
  for (int ni = 0; ni < 8; ++ni)
    pb[ni] = MT + (size_t)(c0 + ni*16 + frow) * NN + kz + kg*8;

  f32x4 acc[4][8] = {};

  #pragma unroll 1
  for (int kt = 0; kt < 16; ++kt) {
    const int ko = kt * 32;
    float4 a0[4], a1[4];
    f16x8 b[8];
    #pragma unroll
    for (int mi = 0; mi < 4; ++mi) {
      a0[mi] = *(const float4*)(pa[mi] + ko);
      a1[mi] = *(const float4*)(pa[mi] + ko + 4);
    }
    #pragma unroll
    for (int ni = 0; ni < 8; ++ni)
      b[ni] = *(const f16x8*)(pb[ni] + ko);
    f16x8 a[4];
    #pragma unroll
    for (int mi = 0; mi < 4; ++mi) {
      F16x8B u;
      u.h2[0] = cvt_pk(a0[mi].x, a0[mi].y);
      u.h2[1] = cvt_pk(a0[mi].z, a0[mi].w);
      u.h2[2] = cvt_pk(a1[mi].x, a1[mi].y);
      u.h2[3] = cvt_pk(a1[mi].z, a1[mi].w);
      a[mi] = u.v;
    }
    #pragma unroll
    for (int mi = 0; mi < 4; ++mi)
      #pragma unroll
      for (int ni = 0; ni < 8; ++ni)
        acc[mi][ni] = __builtin_amdgcn_mfma_f32_16x16x32_f16(a[mi], b[ni], acc[mi][ni], 0, 0, 0);
  }

  f16* Pz = P + (size_t)zt * PLANE_ELEMS;
  #pragma unroll
  for (int mi = 0; mi < 4; ++mi) {
    const int orow = j0 + mi*16 + kg*4;
    #pragma unroll
    for (int ni = 0; ni < 8; ++ni) {
      const int ocol = c0 + ni*16 + frow;
      #pragma unroll
      for (int r4 = 0; r4 < 4; ++r4)
        Pz[(size_t)(orow + r4) * NCOL + ocol] = (f16)acc[mi][ni][r4];
    }
  }
}

// ---------- k7: out[j, i*64+l] = num/den over 8 split-K planes ----------
__global__ __launch_bounds__(256) void k_div(const f16* __restrict__ P,
                                             float* __restrict__ out) {
  const int gid = blockIdx.x * 256 + threadIdx.x;
  const int j = gid >> 9, c = gid & 511, i = c >> 6;
  const size_t rc = (size_t)j*NCOL + c;
  const size_t rd = (size_t)j*NCOL + 512 + i;
  float num = 0.f, den = 0.f;
  #pragma unroll
  for (int z = 0; z < KSPLIT; ++z) {
    const f16* Pz = P + (size_t)z * PLANE_ELEMS;
    num += (float)Pz[rc];
    den += (float)Pz[rd];
  }
  out[gid] = num / den;
}

extern "C" void kernel_launch(void* const* d_in, const int* in_sizes, int n_in,
                              void* d_out, int out_size, void* d_ws, size_t ws_size,
                              hipStream_t stream) {
  const float* node = (const float*)d_in[0];
  const float* adj  = (const float*)d_in[1];
  const float* W    = (const float*)d_in[2];
  const float* sa   = (const float*)d_in[3];
  float* out = (float*)d_out;
  char* ws = (char*)d_ws;
  if (ws_size < (size_t)WS_END) return;

  float* hidden = (float*)(ws + WS_HID);
  float* f2     = (float*)(ws + WS_F2);
  float* mx     = (float*)(ws + WS_MX);
  f16*   MT     = (f16*)(ws + WS_MT);
  f16*   P      = (f16*)(ws + WS_P);

  k_hidden<<<dim3(8, 128),    256, 0, stream>>>(node, W, sa, hidden, f2);
  k_max   <<<dim3(8),         256, 0, stream>>>(f2, mx);
  k_mt_num<<<dim3(8, 128),    256, 0, stream>>>(hidden, f2, mx, MT);
  k_mt_den<<<dim3(16),        256, 0, stream>>>(f2, mx, MT);
  k_gemm  <<<dim3(640),       256, 0, stream>>>(adj, MT, P);
  k_div   <<<dim3(8192),      256, 0, stream>>>(P, out);
}

// Round 11
// 73.604 us; speedup vs baseline: 2.0876x; 2.0876x over previous
//
#include <hip/hip_runtime.h>

#define ALPHA 0.2f
#define NN 4096
#define IN_DIM 128
#define REPR 64
#define HEADS 8
#define NCOL 640   // 512 numerator + 8 denominator + 120 pad (never read)
#define KSPLIT 8
#define PLANE_ELEMS (NN * NCOL)

typedef _Float16 f16;
typedef _Float16 f16x2 __attribute__((ext_vector_type(2)));
typedef _Float16 f16x8 __attribute__((ext_vector_type(8)));
typedef float f32x4 __attribute__((ext_vector_type(4)));

union F16x8U { f16 e[8]; f16x8 v; };
union F16x8B { f16x2 h2[4]; f16x8 v; };

static __device__ __forceinline__ f16x2 cvt_pk(float x, float y) {
  return __builtin_bit_cast(f16x2, __builtin_amdgcn_cvt_pkrtz(x, y));
}

// ws layout (bytes) — ws_size = 256 MiB
#define WS_P   0u            // 8*4096*640*2 = 41943040
#define WS_HID 41943040u     // 8388608
#define WS_F2  50331648u     // 131072
#define WS_MX  50462720u     // 4096
#define WS_MT  50466816u     // 640*4096*2 = 5242880
#define WS_END 55709696u

// ---------- k1: hidden[i,j,l] = sum_k node[j,k]*W[i,k,l] (fp32) + fused f2 ----------
__global__ __launch_bounds__(256) void k_hidden(const float* __restrict__ node,
                                                const float* __restrict__ W,
                                                const float* __restrict__ sa,
                                                float* __restrict__ hidden,
                                                float* __restrict__ f2) {
  const int i = blockIdx.x;
  const int jb = blockIdx.y * 32;
  __shared__ float nl[32][137];
  __shared__ __align__(16) float wl[128][64];
  const int t = threadIdx.x;
  const float4* gn = (const float4*)(node + (size_t)jb * IN_DIM);
  #pragma unroll
  for (int q = 0; q < 4; ++q) {
    int i4 = q * 256 + t;
    int r = i4 >> 5, c4 = i4 & 31;
    float4 v = gn[i4];
    nl[r][c4*4+0] = v.x; nl[r][c4*4+1] = v.y; nl[r][c4*4+2] = v.z; nl[r][c4*4+3] = v.w;
  }
  const float4* gw = (const float4*)(W + (size_t)i * IN_DIM * REPR);
  #pragma unroll
  for (int q = 0; q < 8; ++q) {
    int i4 = q * 256 + t;
    int r = i4 >> 4, c4 = i4 & 15;
    *(float4*)&wl[r][c4*4] = gw[i4];
  }
  __syncthreads();
  const int tx = t & 15, ty = t >> 4;
  float acc0[4] = {0,0,0,0}, acc1[4] = {0,0,0,0};
  #pragma unroll 4
  for (int k = 0; k < 128; ++k) {
    float a0 = nl[2*ty][k], a1 = nl[2*ty+1][k];
    float4 b = *(const float4*)&wl[k][4*tx];
    acc0[0] += a0*b.x; acc0[1] += a0*b.y; acc0[2] += a0*b.z; acc0[3] += a0*b.w;
    acc1[0] += a1*b.x; acc1[1] += a1*b.y; acc1[2] += a1*b.z; acc1[3] += a1*b.w;
  }
  float* o0 = hidden + ((size_t)i*NN + jb + 2*ty) * REPR + 4*tx;
  *(float4*)o0 = make_float4(acc0[0],acc0[1],acc0[2],acc0[3]);
  *(float4*)(o0 + REPR) = make_float4(acc1[0],acc1[1],acc1[2],acc1[3]);

  float4 ad = *(const float4*)(sa + i * 2 * REPR + REPR + 4*tx);
  float s0 = 0.f, s1 = 0.f, x;
  x = acc0[0]; s0 += (x > 0.f ? x : ALPHA*x) * ad.x;
  x = acc0[1]; s0 += (x > 0.f ? x : ALPHA*x) * ad.y;
  x = acc0[2]; s0 += (x > 0.f ? x : ALPHA*x) * ad.z;
  x = acc0[3]; s0 += (x > 0.f ? x : ALPHA*x) * ad.w;
  x = acc1[0]; s1 += (x > 0.f ? x : ALPHA*x) * ad.x;
  x = acc1[1]; s1 += (x > 0.f ? x : ALPHA*x) * ad.y;
  x = acc1[2]; s1 += (x > 0.f ? x : ALPHA*x) * ad.z;
  x = acc1[3]; s1 += (x > 0.f ? x : ALPHA*x) * ad.w;
  #pragma unroll
  for (int d = 8; d > 0; d >>= 1) {
    s0 += __shfl_down(s0, d, 16);
    s1 += __shfl_down(s1, d, 16);
  }
  if (tx == 0) {
    f2[i*NN + jb + 2*ty]     = s0;
    f2[i*NN + jb + 2*ty + 1] = s1;
  }
}

// ---------- k3: per-head max of f2 ----------
__global__ __launch_bounds__(256) void k_max(const float* __restrict__ f2,
                                             float* __restrict__ mx) {
  const int i = blockIdx.x, t = threadIdx.x;
  __shared__ float red[256];
  float m = -1e30f;
  #pragma unroll
  for (int q = 0; q < 16; ++q) m = fmaxf(m, f2[i*NN + q*256 + t]);
  red[t] = m; __syncthreads();
  for (int s = 128; s > 0; s >>= 1) {
    if (t < s) red[t] = fmaxf(red[t], red[t + s]);
    __syncthreads();
  }
  if (t == 0) mx[i] = red[0];
}

// ---------- k4 fused: numerator rows (y<128) + denominator rows (y==128) ----------
__global__ __launch_bounds__(256) void k_mt(const float* __restrict__ hidden,
                                            const float* __restrict__ f2,
                                            const float* __restrict__ mx,
                                            f16* __restrict__ MT) {
  const int i = blockIdx.x;
  const float m = mx[i];
  if (blockIdx.y < 128) {
    const int l = threadIdx.x & 63, q = threadIdx.x >> 6;
    const int k0 = blockIdx.y * 32 + q * 8;
    float g[8];
    #pragma unroll
    for (int kk = 0; kk < 8; ++kk) g[kk] = __expf(f2[i*NN + k0 + kk] - m);
    F16x8U u;
    #pragma unroll
    for (int kk = 0; kk < 8; ++kk) {
      float h = hidden[((size_t)i*NN + k0 + kk) * REPR + l];
      u.e[kk] = (f16)(g[kk] * h);
    }
    *(f16x8*)&MT[(size_t)(i*REPR + l) * NN + k0] = u.v;
  } else {
    #pragma unroll
    for (int q = 0; q < 2; ++q) {
      const int k0 = (threadIdx.x * 2 + q) * 8;
      F16x8U u;
      #pragma unroll
      for (int kk = 0; kk < 8; ++kk) u.e[kk] = (f16)__expf(f2[i*NN + k0 + kk] - m);
      *(f16x8*)&MT[(size_t)(512 + i) * NN + k0] = u.v;
    }
  }
}

// ---------- k6: T3-minimum pipelined GEMM — all-DMA staging, stage(t+1) BEFORE compute(t) ----------
// P[z][j][c] = sum_{k in split z} A[j,k] * MT[c,k].  BM=BN=128, BK=32,
// dbuf LDS 48KB (3 blocks/CU). Per step: issue 6 global_load_lds for tile
// t+1 -> buf^1; ds_read + cvt + 16 MFMA from buf (latency of t+1's loads
// hides under compute); vmcnt(0) [cheap now] + barrier.
// A: fp32 LDS [128][32] (128B rows, 8 slots, XOR c=s^(m&7) via pre-swizzled
//    source); cvt->f16 in regs (0/1 exact).
// B: f16 LDS as 64 super-rows x 128B (2 c-rows each), 8-slot XOR — same
//    structure as the R3-proven zero-conflict layout.
__global__ __launch_bounds__(256) void k_gemm(const float* __restrict__ Af,
                                              const f16* __restrict__ MT,
                                              f16* __restrict__ P) {
  __shared__ __align__(16) float smA[2][128*32];  // 2 x 16KB
  __shared__ __align__(16) f16  smB[2][64*64];    // 2 x 8KB (super-rows)
  const int t = threadIdx.x;
  const int lane = t & 63, wid = t >> 6;

  // XCD swizzle: all 40 blocks (5c x 8z) of a j-tile on one XCD (1280=8*160)
  const int lin = blockIdx.x;
  const int xcd = lin & 7, idx = lin >> 3;   // [0,160)
  const int jt  = xcd + 8 * (idx / 40);      // 0..31
  const int r   = idx % 40;
  const int ct  = r % 5;                     // 0..4
  const int zt  = r / 5;                     // 0..7

  const int c0 = ct * 128;
  const int j0 = jt * 128;
  const int kz = zt * 512;
  const int NK = 16;                         // 16 k-steps of 32

  // A staging: 1024 chunks of 16B (4/thread), pre-swizzled source
  const char* Ab = (const char*)Af;
  size_t ga[4]; int cbA[4];
  #pragma unroll
  for (int q = 0; q < 4; ++q) {
    int ci = q*256 + t;
    int m = ci >> 3, s = ci & 7;
    int c = s ^ (m & 7);
    ga[q]  = ((size_t)(j0 + m) * NN + kz) * 4 + (size_t)c * 16;
    cbA[q] = (q*256 + wid*64) * 16;          // wave-uniform dest base
  }
  // B staging: 512 chunks (2/thread); super-row sr holds c-rows 2sr,2sr+1
  const char* Bb = (const char*)MT;
  size_t gb[2]; int cbB[2];
  #pragma unroll
  for (int q = 0; q < 2; ++q) {
    int ci = q*256 + t;
    int sr = ci >> 3, sl = ci & 7;
    int sp = sl ^ (sr & 7);
    int crow = sr*2 + (sp >> 2), kc = sp & 3;
    gb[q]  = ((size_t)(c0 + crow) * NN + kz) * 2 + (size_t)kc * 16;
    cbB[q] = (q*256 + wid*64) * 16;
  }

  const int frow = lane & 15, kg = lane >> 4;
  const int wr = wid >> 1, wc = wid & 1;
  int arow[4], aoff[2], boff[4];
  #pragma unroll
  for (int mi = 0; mi < 4; ++mi) arow[mi] = (wr*64 + mi*16 + frow) * 128; // bytes
  #pragma unroll
  for (int h = 0; h < 2; ++h) aoff[h] = ((2*kg + h) ^ (frow & 7)) * 16;
  #pragma unroll
  for (int ni = 0; ni < 4; ++ni) {
    int row = wc*64 + ni*16 + frow;
    int sr = row >> 1, h = row & 1;
    int slot = (h*4 + kg) ^ (sr & 7);
    boff[ni] = sr*128 + slot*16;             // bytes
  }

#define STAGE(BUF, KT) do { \
    const size_t kbA_ = (size_t)(KT) * 128;  /* 32 f32 */ \
    const size_t kbB_ = (size_t)(KT) * 64;   /* 32 f16 */ \
    _Pragma("unroll") \
    for (int q = 0; q < 4; ++q) \
      __builtin_amdgcn_global_load_lds( \
        (const __attribute__((address_space(1))) void*)(Ab + ga[q] + kbA_), \
        (__attribute__((address_space(3))) void*)((char*)smA[BUF] + cbA[q]), 16, 0, 0); \
    _Pragma("unroll") \
    for (int q = 0; q < 2; ++q) \
      __builtin_amdgcn_global_load_lds( \
        (const __attribute__((address_space(1))) void*)(Bb + gb[q] + kbB_), \
        (__attribute__((address_space(3))) void*)((char*)smB[BUF] + cbB[q]), 16, 0, 0); \
  } while (0)

  f32x4 acc[4][4] = {};

  // prologue: tile 0 staged and drained once (exposed latency paid once)
  STAGE(0, 0);
  asm volatile("s_waitcnt vmcnt(0)" ::: "memory");
  __builtin_amdgcn_s_barrier();

  #pragma unroll 1
  for (int kt = 0; kt < NK; ++kt) {
    const int cur = kt & 1;
    if (kt + 1 < NK) STAGE(cur ^ 1, kt + 1);   // issue BEFORE compute
    const char* bufA = (const char*)smA[cur];
    const char* bufB = (const char*)smB[cur];
    f16x8 a[4], b[4];
    #pragma unroll
    for (int mi = 0; mi < 4; ++mi) {
      float4 lo = *(const float4*)(bufA + arow[mi] + aoff[0]);
      float4 hi = *(const float4*)(bufA + arow[mi] + aoff[1]);
      F16x8B u;
      u.h2[0] = cvt_pk(lo.x, lo.y);
      u.h2[1] = cvt_pk(lo.z, lo.w);
      u.h2[2] = cvt_pk(hi.x, hi.y);
      u.h2[3] = cvt_pk(hi.z, hi.w);
      a[mi] = u.v;
    }
    #pragma unroll
    for (int ni = 0; ni < 4; ++ni)
      b[ni] = *(const f16x8*)(bufB + boff[ni]);
    #pragma unroll
    for (int mi = 0; mi < 4; ++mi)
      #pragma unroll
      for (int ni = 0; ni < 4; ++ni)
        acc[mi][ni] = __builtin_amdgcn_mfma_f32_16x16x32_f16(a[mi], b[ni], acc[mi][ni], 0, 0, 0);
    asm volatile("s_waitcnt vmcnt(0)" ::: "memory");  // t+1 loads (mostly landed)
    __builtin_amdgcn_s_barrier();
  }

  f16* Pz = P + (size_t)zt * PLANE_ELEMS;
  #pragma unroll
  for (int mi = 0; mi < 4; ++mi) {
    const int orow = j0 + wr*64 + mi*16 + kg*4;
    #pragma unroll
    for (int ni = 0; ni < 4; ++ni) {
      const int ocol = c0 + wc*64 + ni*16 + frow;
      #pragma unroll
      for (int r4 = 0; r4 < 4; ++r4)
        Pz[(size_t)(orow + r4) * NCOL + ocol] = (f16)acc[mi][ni][r4];
    }
  }
#undef STAGE
}

// ---------- k7: out[j, i*64+l] = num/den over 8 split-K planes ----------
__global__ __launch_bounds__(256) void k_div(const f16* __restrict__ P,
                                             float* __restrict__ out) {
  const int gid = blockIdx.x * 256 + threadIdx.x;
  const int j = gid >> 9, c = gid & 511, i = c >> 6;
  const size_t rc = (size_t)j*NCOL + c;
  const size_t rd = (size_t)j*NCOL + 512 + i;
  float num = 0.f, den = 0.f;
  #pragma unroll
  for (int z = 0; z < KSPLIT; ++z) {
    const f16* Pz = P + (size_t)z * PLANE_ELEMS;
    num += (float)Pz[rc];
    den += (float)Pz[rd];
  }
  out[gid] = num / den;
}

extern "C" void kernel_launch(void* const* d_in, const int* in_sizes, int n_in,
                              void* d_out, int out_size, void* d_ws, size_t ws_size,
                              hipStream_t stream) {
  const float* node = (const float*)d_in[0];
  const float* adj  = (const float*)d_in[1];
  const float* W    = (const float*)d_in[2];
  const float* sa   = (const float*)d_in[3];
  float* out = (float*)d_out;
  char* ws = (char*)d_ws;
  if (ws_size < (size_t)WS_END) return;

  float* hidden = (float*)(ws + WS_HID);
  float* f2     = (float*)(ws + WS_F2);
  float* mx     = (float*)(ws + WS_MX);
  f16*   MT     = (f16*)(ws + WS_MT);
  f16*   P      = (f16*)(ws + WS_P);

  k_hidden<<<dim3(8, 128),    256, 0, stream>>>(node, W, sa, hidden, f2);
  k_max   <<<dim3(8),         256, 0, stream>>>(f2, mx);
  k_mt    <<<dim3(8, 129),    256, 0, stream>>>(hidden, f2, mx, MT);
  k_gemm  <<<dim3(1280),      256, 0, stream>>>(adj, MT, P);
  k_div   <<<dim3(8192),      256, 0, stream>>>(P, out);
}